// Round 2
// baseline (387.417 us; speedup 1.0000x reference)
//
#include <hip/hip_runtime.h>

// EquivariantLayer on MI355X (gfx950).
// f[16][8][64][64], kernel[1][8][16][64][64] -> out[16][128][128][128]
//
// Pipeline (all scratch in d_ws, ~29.7 MB):
//   1. rfft2_fused : 256 blocks (128 f imgs + 128 symmetrized kernel imgs)
//                    -> Fv[128][2112] cplx, Kv[128][2112] cplx
//   2. conv_mul    : CV[b,j] = sum_i F[b,i]*K[i,j]      -> CVv[256][2112] cplx
//   3. irfft_stepA : x-inverse DFT (64 ks -> 128 x), upsample+TO_U/TO_V folded
//                    -> G[640][128][32] cplx   (imgs: 512 uv + 128 fr)
//   4. irfft_stepB : y-inverse (real), parity-folded -> u(ch 64+j), v(ch 96+j),
//                    fr(ch c) written into d_out
//   5. cross       : out[8+p] = u_i v_j - u_j v_i  (channels 8..127)
//
// DFT conventions (identical formulas to the verified round-1 kernel):
//   scale = (ky==0 ? 2 : 4)/16384 (upsample x2, Hermitian x2, 1/(128*128))
//   ks<=32 -> kk=ks ; ks>=33 -> kk=ks+64 ; nyquist row ks==32 / col ky==32 zeroed
//   parity: G[x0+64] = even(ks)-sum minus odd(ks)-sum (since (-1)^kk == (-1)^ks)

#define PI_D 3.14159265358979323846

// ---------------- 1. forward rfft2 of 64x64 images (f + symmetrized kernel) --
__global__ __launch_bounds__(512) void rfft2_fused_kernel(
    const float* __restrict__ f, const float* __restrict__ kern,
    float* __restrict__ Fv, float* __restrict__ Kv) {
  __shared__ float s_img[64][64];
  __shared__ float s_fe[64][32];
  __shared__ float s_fo[64][32];
  __shared__ __align__(16) float2 s_f[64][33];
  __shared__ float2 s_tw[64];

  const int bid = blockIdx.x;
  const int tid = threadIdx.x;
  const int sym = (bid >= 128);
  const float* img = sym ? (kern + (size_t)(bid - 128) * 4096)
                         : (f + (size_t)bid * 4096);
  float* dst = sym ? (Kv + (size_t)(bid - 128) * 4224)
                   : (Fv + (size_t)bid * 4224);  // 2112 cplx = 4224 floats

  if (tid < 64) {
    double a = -2.0 * PI_D * (double)tid / 64.0;  // forward sign
    s_tw[tid] = make_float2((float)cos(a), (float)sin(a));
  }
  for (int idx = tid; idx < 4096; idx += 512) {
    int i = idx >> 6, j = idx & 63;
    float v;
    if (sym) {
      int ni = (64 - i) & 63, nj = (64 - j) & 63;
      v = (img[i * 64 + j] + img[nj * 64 + i] + img[ni * 64 + nj] + img[j * 64 + ni] +
           img[j * 64 + i] + img[i * 64 + nj] + img[nj * 64 + ni] + img[ni * 64 + j]) *
          0.125f;
    } else {
      v = img[idx];
    }
    s_img[i][j] = v;
  }
  __syncthreads();
  // parity fold along y
  for (int o = tid; o < 2048; o += 512) {
    int x = o >> 5, y = o & 31;
    float s0 = s_img[x][y], s1 = s_img[x][y + 32];
    s_fe[x][y] = s0 + s1;
    s_fo[x][y] = s0 - s1;
  }
  __syncthreads();
  // pass 1: rows along y (real -> 33 cplx), 32 MACs each via parity
  for (int o = tid; o < 2112; o += 512) {
    int x = o / 33, ky = o - x * 33;
    const float* row = (ky & 1) ? s_fo[x] : s_fe[x];
    float re = 0.f, im = 0.f;
    int t = 0;
#pragma unroll 8
    for (int y = 0; y < 32; ++y) {
      float a = row[y];
      float2 w = s_tw[t];
      re += a * w.x;
      im += a * w.y;
      t = (t + ky) & 63;
    }
    s_f[x][ky] = make_float2(re, im);
  }
  __syncthreads();
  // pass 2: cols along x, output pairs (kx0, kx0+32) via x-parity
  for (int o = tid; o < 1056; o += 512) {
    int kx0 = o / 33, ky = o - kx0 * 33;
    float er = 0.f, ei = 0.f, orr = 0.f, oi = 0.f;
    int t = 0;
#pragma unroll 8
    for (int x = 0; x < 64; ++x) {
      float2 cv = s_f[x][ky];
      float2 w = s_tw[t];
      float pr = cv.x * w.x - cv.y * w.y;
      float pi = cv.x * w.y + cv.y * w.x;
      if (x & 1) { orr += pr; oi += pi; } else { er += pr; ei += pi; }
      t = (t + kx0) & 63;
    }
    float2* o2 = (float2*)dst;
    o2[kx0 * 33 + ky] = make_float2(er + orr, ei + oi);
    o2[(kx0 + 32) * 33 + ky] = make_float2(er - orr, ei - oi);
  }
}

// ---------------- 2. channel mixing ----------------
__global__ __launch_bounds__(256) void conv_mul_kernel(const float* __restrict__ Fv,
                                                       const float* __restrict__ Kv,
                                                       float* __restrict__ CVv) {
  int idx = blockIdx.x * 256 + threadIdx.x;  // over 16*16*2112
  if (idx >= 16 * 16 * 2112) return;
  int xy = idx % 2112;
  int t = idx / 2112;
  int j = t & 15, b = t >> 4;
  const float2* F2 = (const float2*)Fv;
  const float2* K2 = (const float2*)Kv;
  float re = 0.f, im = 0.f;
#pragma unroll
  for (int i = 0; i < 8; ++i) {
    float2 fv = F2[(b * 8 + i) * 2112 + xy];
    float2 kv = K2[(i * 16 + j) * 2112 + xy];
    re += fv.x * kv.x - fv.y * kv.y;
    im += fv.x * kv.y + fv.y * kv.x;
  }
  ((float2*)CVv)[idx] = make_float2(re, im);
}

// ---------------- 3. step A: x-inverse, 640 images -> G ----------------
// img < 512: uv (b=img>>5, r=img&31, j=r>>1, ph=r&1), src=CV[b*16+j]
// img >=512: fr (idx=img-512), src=F[idx]
__global__ __launch_bounds__(256) void irfft_stepA_kernel(
    const float* __restrict__ CVv, const float* __restrict__ Fv,
    float* __restrict__ G) {
  __shared__ __align__(16) float2 s_c[64][34];
  __shared__ float2 s_tw[128];
  const int img = blockIdx.x;
  const int tid = threadIdx.x;

  const float2* src;
  int ph = 0, is_uv = (img < 512);
  if (is_uv) {
    int b = img >> 5, r = img & 31, j = r >> 1;
    ph = r & 1;
    src = (const float2*)Fv;  // placeholder, overwritten below
    src = (const float2*)CVv + (size_t)(b * 16 + j) * 2112;
  } else {
    src = (const float2*)Fv + (size_t)(img - 512) * 2112;
  }

  if (tid < 128) {
    double a = 2.0 * PI_D * (double)tid / 128.0;  // inverse sign
    s_tw[tid] = make_float2((float)cos(a), (float)sin(a));
  }
  for (int o = tid; o < 2112; o += 256) {
    int ks = o / 33, ky = o - ks * 33;
    float2 cv = src[o];
    float scale = ((ky == 0) ? 2.0f : 4.0f) * (1.0f / 16384.0f);
    if (ks == 32 || ky == 32) scale = 0.0f;
    float re, im;
    if (is_uv) {
      int kx = (ks <= 32) ? ks : ks - 64;
      float fac = 0.0f;
      if ((kx | ky) != 0) {
        float invden = 1.0f / (float)(kx * kx + ky * ky);
        fac = (ph == 0) ? ((float)ky * invden) : (-(float)kx * invden);
      }
      fac *= scale;
      re = -cv.y * fac;  // (re,im) * (i*fac)
      im = cv.x * fac;
    } else {
      re = cv.x * scale;
      im = cv.y * scale;
    }
    s_c[ks][ky] = make_float2(re, im);
  }
  __syncthreads();

  const int kyg = tid & 15, xg = tid >> 4;
  const int ky0 = kyg * 2;

  float aer[2][4], aei[2][4], aor[2][4], aoi[2][4];
#pragma unroll
  for (int jj = 0; jj < 2; ++jj)
#pragma unroll
    for (int i = 0; i < 4; ++i) { aer[jj][i] = aei[jj][i] = aor[jj][i] = aoi[jj][i] = 0.f; }

  float twr[4], twi[4], w1r[4], w1i[4];
#pragma unroll
  for (int i = 0; i < 4; ++i) {
    float2 w = s_tw[4 * xg + i];
    w1r[i] = w.x; w1i[i] = w.y;
    twr[i] = 1.f; twi[i] = 0.f;
  }
  // sub-loop 1: ks=0..32 (kk=ks), twiddle recurrence tw *= W^{x0}
#pragma unroll
  for (int ks = 0; ks <= 32; ++ks) {
    float4 cc = *(const float4*)(&s_c[ks][ky0]);
#pragma unroll
    for (int i = 0; i < 4; ++i) {
      float pr0 = cc.x * twr[i] - cc.y * twi[i];
      float pi0 = cc.x * twi[i] + cc.y * twr[i];
      float pr1 = cc.z * twr[i] - cc.w * twi[i];
      float pi1 = cc.z * twi[i] + cc.w * twr[i];
      if (ks & 1) {
        aor[0][i] += pr0; aoi[0][i] += pi0; aor[1][i] += pr1; aoi[1][i] += pi1;
      } else {
        aer[0][i] += pr0; aei[0][i] += pi0; aer[1][i] += pr1; aei[1][i] += pi1;
      }
      float nr = twr[i] * w1r[i] - twi[i] * w1i[i];
      twi[i] = twr[i] * w1i[i] + twi[i] * w1r[i];
      twr[i] = nr;
    }
  }
  // sub-loop 2: ks=33..63 (kk=ks+64 = 97..127), re-init from table
#pragma unroll
  for (int i = 0; i < 4; ++i) {
    float2 w = s_tw[(97 * (4 * xg + i)) & 127];
    twr[i] = w.x; twi[i] = w.y;
  }
#pragma unroll
  for (int ks = 33; ks < 64; ++ks) {
    float4 cc = *(const float4*)(&s_c[ks][ky0]);
#pragma unroll
    for (int i = 0; i < 4; ++i) {
      float pr0 = cc.x * twr[i] - cc.y * twi[i];
      float pi0 = cc.x * twi[i] + cc.y * twr[i];
      float pr1 = cc.z * twr[i] - cc.w * twi[i];
      float pi1 = cc.z * twi[i] + cc.w * twr[i];
      if (ks & 1) {
        aor[0][i] += pr0; aoi[0][i] += pi0; aor[1][i] += pr1; aoi[1][i] += pi1;
      } else {
        aer[0][i] += pr0; aei[0][i] += pi0; aer[1][i] += pr1; aei[1][i] += pi1;
      }
      float nr = twr[i] * w1r[i] - twi[i] * w1i[i];
      twi[i] = twr[i] * w1i[i] + twi[i] * w1r[i];
      twr[i] = nr;
    }
  }

  float2* Gp = (float2*)G + (size_t)img * 128 * 32;
#pragma unroll
  for (int i = 0; i < 4; ++i) {
    int x0 = 4 * xg + i;
#pragma unroll
    for (int jj = 0; jj < 2; ++jj) {
      int ky = ky0 + jj;
      Gp[x0 * 32 + ky] =
          make_float2(aer[jj][i] + aor[jj][i], aei[jj][i] + aoi[jj][i]);
      Gp[(x0 + 64) * 32 + ky] =
          make_float2(aer[jj][i] - aor[jj][i], aei[jj][i] - aoi[jj][i]);
    }
  }
}

// ---------------- 4. step B: y-inverse (real), writes u/v/fr channels --------
__global__ __launch_bounds__(256) void irfft_stepB_kernel(
    const float* __restrict__ G, float* __restrict__ out) {
  __shared__ float2 s_tw[128];
  const int img = blockIdx.x;
  const int tid = threadIdx.x;
  if (tid < 128) {
    double a = 2.0 * PI_D * (double)tid / 128.0;
    s_tw[tid] = make_float2((float)cos(a), (float)sin(a));
  }
  __syncthreads();

  const int y0 = tid & 63, xg = tid >> 6;  // wave = xg, lanes = consecutive y0
  int bch;
  if (img < 512) {
    int b = img >> 5, r = img & 31, j = r >> 1, ph = r & 1;
    bch = b * 128 + ((ph == 0) ? 64 : 96) + j;
  } else {
    int idx = img - 512;
    bch = (idx >> 3) * 128 + (idx & 7);
  }
  float* dst = out + (size_t)bch * 16384;

  // tw[k] = W128^{k*y0} via recurrence
  float twr[32], twi[32];
  float2 w1 = s_tw[y0];
  twr[0] = 1.f; twi[0] = 0.f;
#pragma unroll
  for (int k = 1; k < 32; ++k) {
    twr[k] = twr[k - 1] * w1.x - twi[k - 1] * w1.y;
    twi[k] = twr[k - 1] * w1.y + twi[k - 1] * w1.x;
  }

  for (int xx = 0; xx < 32; ++xx) {
    int x = xg * 32 + xx;
    const float4* g4 = (const float4*)(G + ((size_t)img * 128 + x) * 64);
    float se = 0.f, so = 0.f;
#pragma unroll
    for (int m = 0; m < 16; ++m) {
      float4 g = g4[m];
      se += g.x * twr[2 * m] - g.y * twi[2 * m];
      so += g.z * twr[2 * m + 1] - g.w * twi[2 * m + 1];
    }
    dst[x * 128 + y0] = se + so;
    dst[x * 128 + y0 + 64] = se - so;
  }
}

// ---------------- 5. cross products, register version ----------------
__global__ __launch_bounds__(256) void cross_kernel(float* __restrict__ out) {
  const int b = blockIdx.x >> 6;       // 64 chunks of 256 points
  const int chunk = blockIdx.x & 63;
  const int p = chunk * 256 + threadIdx.x;
  float* base = out + (size_t)b * 128 * 16384;
  float u[16], v[16];
#pragma unroll
  for (int ch = 0; ch < 16; ++ch) u[ch] = base[(size_t)(64 + ch) * 16384 + p];
#pragma unroll
  for (int ch = 0; ch < 16; ++ch) v[ch] = base[(size_t)(96 + ch) * 16384 + p];
  int pp = 0;
#pragma unroll
  for (int i = 0; i < 15; ++i) {
#pragma unroll
    for (int j = i + 1; j < 16; ++j) {
      base[(size_t)(8 + pp) * 16384 + p] = u[i] * v[j] - u[j] * v[i];
      ++pp;
    }
  }
}

extern "C" void kernel_launch(void* const* d_in, const int* in_sizes, int n_in,
                              void* d_out, int out_size, void* d_ws, size_t ws_size,
                              hipStream_t stream) {
  const float* f = (const float*)d_in[0];     // [16][8][64][64]
  const float* kern = (const float*)d_in[1];  // [1][8][16][64][64]
  float* out = (float*)d_out;                 // [16][128][128][128]
  float* ws = (float*)d_ws;

  float* Fv = ws;                   // 128 imgs * 2112 cplx = 540672 floats
  float* Kv = ws + 540672;          // 540672 floats
  float* CVv = ws + 1081344;        // 256 imgs * 2112 cplx = 1081344 floats
  float* G = ws + 2162688;          // 640*128*32 cplx = 5242880 floats (total ~29.7 MB)

  rfft2_fused_kernel<<<256, 512, 0, stream>>>(f, kern, Fv, Kv);
  conv_mul_kernel<<<2112, 256, 0, stream>>>(Fv, Kv, CVv);
  irfft_stepA_kernel<<<640, 256, 0, stream>>>(CVv, Fv, G);
  irfft_stepB_kernel<<<640, 256, 0, stream>>>(G, out);
  cross_kernel<<<1024, 256, 0, stream>>>(out);
}

// Round 3
// 261.769 us; speedup vs baseline: 1.4800x; 1.4800x over previous
//
#include <hip/hip_runtime.h>

// EquivariantLayer on MI355X (gfx950).
// f[16][8][64][64], kernel[1][8][16][64][64] -> out[16][128][128][128]
//
// Pipeline (all scratch in d_ws, ~29.7 MB):
//   1. rfft2_fused : 256 blocks -> Fv[128][2112] cplx, Kv[128][2112] cplx
//   2. conv_mul    : CV[b,j] = sum_i F[b,i]*K[i,j] -> CVv[256][2112] cplx
//   3. irfft_stepA : x-inverse DFT (64 ks -> 128 x) -> G[640][128][32] cplx
//      residue-class trick: S_r = sum_{ks==r mod 4} C[ks] W^{kk ks x0};
//      G[x0+32m] = sum_r i^{r m} S_r  (W^{32kk}=i^{ks mod4}, W^{64kk}=(-1)^ks)
//   4. irfft_stepB : y-inverse (real) -> u(ch 64+j), v(ch 96+j), fr(ch c)
//   5. cross       : out[8+p] = u_i v_j - u_j v_i (channels 8..127)
//
// DFT conventions: scale=(ky==0?2:4)/16384; ks<=32 -> kk=ks, ks>=33 -> kk=ks+64;
// nyquist row ks==32 / col ky==32 zeroed (so the L2 loop may run ks=32 with the
// wrong twiddle: C[32]==0).

#define PI_D 3.14159265358979323846

// ---------------- 1. forward rfft2 of 64x64 images (f + symmetrized kernel) --
__global__ __launch_bounds__(512) void rfft2_fused_kernel(
    const float* __restrict__ f, const float* __restrict__ kern,
    float* __restrict__ Fv, float* __restrict__ Kv) {
  __shared__ float s_img[64][64];
  __shared__ float s_fe[64][32];
  __shared__ float s_fo[64][32];
  __shared__ __align__(16) float2 s_f[64][33];
  __shared__ float2 s_tw[64];

  const int bid = blockIdx.x;
  const int tid = threadIdx.x;
  const int sym = (bid >= 128);
  const float* img = sym ? (kern + (size_t)(bid - 128) * 4096)
                         : (f + (size_t)bid * 4096);
  float* dst = sym ? (Kv + (size_t)(bid - 128) * 4224)
                   : (Fv + (size_t)bid * 4224);

  if (tid < 64) {
    double a = -2.0 * PI_D * (double)tid / 64.0;  // forward sign
    s_tw[tid] = make_float2((float)cos(a), (float)sin(a));
  }
  for (int idx = tid; idx < 4096; idx += 512) {
    int i = idx >> 6, j = idx & 63;
    float v;
    if (sym) {
      int ni = (64 - i) & 63, nj = (64 - j) & 63;
      v = (img[i * 64 + j] + img[nj * 64 + i] + img[ni * 64 + nj] + img[j * 64 + ni] +
           img[j * 64 + i] + img[i * 64 + nj] + img[nj * 64 + ni] + img[ni * 64 + j]) *
          0.125f;
    } else {
      v = img[idx];
    }
    s_img[i][j] = v;
  }
  __syncthreads();
  for (int o = tid; o < 2048; o += 512) {
    int x = o >> 5, y = o & 31;
    float s0 = s_img[x][y], s1 = s_img[x][y + 32];
    s_fe[x][y] = s0 + s1;
    s_fo[x][y] = s0 - s1;
  }
  __syncthreads();
  for (int o = tid; o < 2112; o += 512) {
    int x = o / 33, ky = o - x * 33;
    const float* row = (ky & 1) ? s_fo[x] : s_fe[x];
    float re = 0.f, im = 0.f;
    int t = 0;
#pragma unroll 8
    for (int y = 0; y < 32; ++y) {
      float a = row[y];
      float2 w = s_tw[t];
      re += a * w.x;
      im += a * w.y;
      t = (t + ky) & 63;
    }
    s_f[x][ky] = make_float2(re, im);
  }
  __syncthreads();
  for (int o = tid; o < 1056; o += 512) {
    int kx0 = o / 33, ky = o - kx0 * 33;
    float er = 0.f, ei = 0.f, orr = 0.f, oi = 0.f;
    int t = 0;
#pragma unroll 8
    for (int x = 0; x < 64; ++x) {
      float2 cv = s_f[x][ky];
      float2 w = s_tw[t];
      float pr = cv.x * w.x - cv.y * w.y;
      float pi = cv.x * w.y + cv.y * w.x;
      if (x & 1) { orr += pr; oi += pi; } else { er += pr; ei += pi; }
      t = (t + kx0) & 63;
    }
    float2* o2 = (float2*)dst;
    o2[kx0 * 33 + ky] = make_float2(er + orr, ei + oi);
    o2[(kx0 + 32) * 33 + ky] = make_float2(er - orr, ei - oi);
  }
}

// ---------------- 2. channel mixing ----------------
__global__ __launch_bounds__(256) void conv_mul_kernel(const float* __restrict__ Fv,
                                                       const float* __restrict__ Kv,
                                                       float* __restrict__ CVv) {
  int idx = blockIdx.x * 256 + threadIdx.x;
  if (idx >= 16 * 16 * 2112) return;
  int xy = idx % 2112;
  int t = idx / 2112;
  int j = t & 15, b = t >> 4;
  const float2* F2 = (const float2*)Fv;
  const float2* K2 = (const float2*)Kv;
  float re = 0.f, im = 0.f;
#pragma unroll
  for (int i = 0; i < 8; ++i) {
    float2 fv = F2[(b * 8 + i) * 2112 + xy];
    float2 kv = K2[(i * 16 + j) * 2112 + xy];
    re += fv.x * kv.x - fv.y * kv.y;
    im += fv.x * kv.y + fv.y * kv.x;
  }
  ((float2*)CVv)[idx] = make_float2(re, im);
}

// ---------------- 3. step A: x-inverse, residue-class, low-VGPR ----------------
// thread: x0 = tid&31 (covers x0, x0+32, x0+64, x0+96), kyg = tid>>5 (4 ky each)
__global__ __launch_bounds__(256) void irfft_stepA_kernel(
    const float* __restrict__ CVv, const float* __restrict__ Fv,
    float* __restrict__ G) {
  __shared__ __align__(16) float2 s_c[64][34];
  __shared__ float2 s_tw[128];
  const int img = blockIdx.x;
  const int tid = threadIdx.x;

  const float2* src;
  int ph = 0;
  const int is_uv = (img < 512);
  if (is_uv) {
    int b = img >> 5, r = img & 31, j = r >> 1;
    ph = r & 1;
    src = (const float2*)CVv + (size_t)(b * 16 + j) * 2112;
  } else {
    src = (const float2*)Fv + (size_t)(img - 512) * 2112;
  }

  if (tid < 128) {
    double a = 2.0 * PI_D * (double)tid / 128.0;  // inverse sign
    s_tw[tid] = make_float2((float)cos(a), (float)sin(a));
  }
  for (int o = tid; o < 2112; o += 256) {
    int ks = o / 33, ky = o - ks * 33;
    float2 cv = src[o];
    float scale = ((ky == 0) ? 2.0f : 4.0f) * (1.0f / 16384.0f);
    if (ks == 32 || ky == 32) scale = 0.0f;
    float re, im;
    if (is_uv) {
      int kx = (ks <= 32) ? ks : ks - 64;
      float fac = 0.0f;
      if ((kx | ky) != 0) {
        float invden = 1.0f / (float)(kx * kx + ky * ky);
        fac = (ph == 0) ? ((float)ky * invden) : (-(float)kx * invden);
      }
      fac *= scale;
      re = -cv.y * fac;  // (re,im) * (i*fac)
      im = cv.x * fac;
    } else {
      re = cv.x * scale;
      im = cv.y * scale;
    }
    s_c[ks][ky] = make_float2(re, im);
  }
  __syncthreads();

  const int x0 = tid & 31;
  const int ky0 = (tid >> 5) * 4;

  float Sr[4][4], Si[4][4];  // [residue r][ky u]
#pragma unroll
  for (int r = 0; r < 4; ++r)
#pragma unroll
    for (int u = 0; u < 4; ++u) { Sr[r][u] = 0.f; Si[r][u] = 0.f; }

  const float2 w1 = s_tw[x0];
  float wr = 1.f, wi = 0.f;  // W^{kk*x0}, kk=0
  // L1: ks = 0..31 (kk = ks)
  for (int kb = 0; kb < 32; kb += 4) {
#pragma unroll
    for (int r = 0; r < 4; ++r) {
      int ks = kb + r;
      float4 c01 = *(const float4*)(&s_c[ks][ky0]);
      float4 c23 = *(const float4*)(&s_c[ks][ky0 + 2]);
      Sr[r][0] += c01.x * wr - c01.y * wi;  Si[r][0] += c01.x * wi + c01.y * wr;
      Sr[r][1] += c01.z * wr - c01.w * wi;  Si[r][1] += c01.z * wi + c01.w * wr;
      Sr[r][2] += c23.x * wr - c23.y * wi;  Si[r][2] += c23.x * wi + c23.y * wr;
      Sr[r][3] += c23.z * wr - c23.w * wi;  Si[r][3] += c23.z * wi + c23.w * wr;
      float nr = wr * w1.x - wi * w1.y;
      wi = wr * w1.y + wi * w1.x;
      wr = nr;
    }
  }
  // L2: ks = 32..63 (kk = ks+64; ks==32 term is zero so its twiddle is moot)
  {
    float2 w0 = s_tw[(96 * x0) & 127];
    wr = w0.x; wi = w0.y;
  }
  for (int kb = 32; kb < 64; kb += 4) {
#pragma unroll
    for (int r = 0; r < 4; ++r) {
      int ks = kb + r;
      float4 c01 = *(const float4*)(&s_c[ks][ky0]);
      float4 c23 = *(const float4*)(&s_c[ks][ky0 + 2]);
      Sr[r][0] += c01.x * wr - c01.y * wi;  Si[r][0] += c01.x * wi + c01.y * wr;
      Sr[r][1] += c01.z * wr - c01.w * wi;  Si[r][1] += c01.z * wi + c01.w * wr;
      Sr[r][2] += c23.x * wr - c23.y * wi;  Si[r][2] += c23.x * wi + c23.y * wr;
      Sr[r][3] += c23.z * wr - c23.w * wi;  Si[r][3] += c23.z * wi + c23.w * wr;
      float nr = wr * w1.x - wi * w1.y;
      wi = wr * w1.y + wi * w1.x;
      wr = nr;
    }
  }

  // combine: G[x0+32m] = sum_r i^{r*m} S_r
  float2* Gp = (float2*)G + (size_t)img * 128 * 32;
#pragma unroll
  for (int u = 0; u < 4; ++u) {
    int ky = ky0 + u;
    float ar = Sr[0][u] + Sr[2][u], ai = Si[0][u] + Si[2][u];   // S0+S2
    float br = Sr[0][u] - Sr[2][u], bi = Si[0][u] - Si[2][u];   // S0-S2
    float cr = Sr[1][u] + Sr[3][u], ci = Si[1][u] + Si[3][u];   // S1+S3
    float dr = Sr[1][u] - Sr[3][u], di = Si[1][u] - Si[3][u];   // S1-S3
    Gp[x0 * 32 + ky]        = make_float2(ar + cr, ai + ci);
    Gp[(x0 + 32) * 32 + ky] = make_float2(br - di, bi + dr);    // b + i*d
    Gp[(x0 + 64) * 32 + ky] = make_float2(ar - cr, ai - ci);
    Gp[(x0 + 96) * 32 + ky] = make_float2(br + di, bi - dr);    // b - i*d
  }
}

// ---------------- 4. step B: y-inverse (real), writes u/v/fr channels --------
__global__ __launch_bounds__(256) void irfft_stepB_kernel(
    const float* __restrict__ G, float* __restrict__ out) {
  __shared__ float2 s_tw[128];
  const int img = blockIdx.x;
  const int tid = threadIdx.x;
  if (tid < 128) {
    double a = 2.0 * PI_D * (double)tid / 128.0;
    s_tw[tid] = make_float2((float)cos(a), (float)sin(a));
  }
  __syncthreads();

  const int y0 = tid & 63, xg = tid >> 6;
  int bch;
  if (img < 512) {
    int b = img >> 5, r = img & 31, j = r >> 1, ph = r & 1;
    bch = b * 128 + ((ph == 0) ? 64 : 96) + j;
  } else {
    int idx = img - 512;
    bch = (idx >> 3) * 128 + (idx & 7);
  }
  float* dst = out + (size_t)bch * 16384;

  float twr[32], twi[32];
  float2 w1 = s_tw[y0];
  twr[0] = 1.f; twi[0] = 0.f;
#pragma unroll
  for (int k = 1; k < 32; ++k) {
    twr[k] = twr[k - 1] * w1.x - twi[k - 1] * w1.y;
    twi[k] = twr[k - 1] * w1.y + twi[k - 1] * w1.x;
  }

  for (int xx = 0; xx < 32; ++xx) {
    int x = xg * 32 + xx;
    const float4* g4 = (const float4*)(G + ((size_t)img * 128 + x) * 64);
    float se = 0.f, so = 0.f;
#pragma unroll
    for (int m = 0; m < 16; ++m) {
      float4 g = g4[m];
      se += g.x * twr[2 * m] - g.y * twi[2 * m];
      so += g.z * twr[2 * m + 1] - g.w * twi[2 * m + 1];
    }
    dst[x * 128 + y0] = se + so;
    dst[x * 128 + y0 + 64] = se - so;
  }
}

// ---------------- 5. cross products, register version ----------------
__global__ __launch_bounds__(256) void cross_kernel(float* __restrict__ out) {
  const int b = blockIdx.x >> 6;
  const int chunk = blockIdx.x & 63;
  const int p = chunk * 256 + threadIdx.x;
  float* base = out + (size_t)b * 128 * 16384;
  float u[16], v[16];
#pragma unroll
  for (int ch = 0; ch < 16; ++ch) u[ch] = base[(size_t)(64 + ch) * 16384 + p];
#pragma unroll
  for (int ch = 0; ch < 16; ++ch) v[ch] = base[(size_t)(96 + ch) * 16384 + p];
  int pp = 0;
#pragma unroll
  for (int i = 0; i < 15; ++i) {
#pragma unroll
    for (int j = i + 1; j < 16; ++j) {
      base[(size_t)(8 + pp) * 16384 + p] = u[i] * v[j] - u[j] * v[i];
      ++pp;
    }
  }
}

extern "C" void kernel_launch(void* const* d_in, const int* in_sizes, int n_in,
                              void* d_out, int out_size, void* d_ws, size_t ws_size,
                              hipStream_t stream) {
  const float* f = (const float*)d_in[0];     // [16][8][64][64]
  const float* kern = (const float*)d_in[1];  // [1][8][16][64][64]
  float* out = (float*)d_out;                 // [16][128][128][128]
  float* ws = (float*)d_ws;

  float* Fv = ws;                   // 128 imgs * 2112 cplx
  float* Kv = ws + 540672;
  float* CVv = ws + 1081344;        // 256 imgs * 2112 cplx
  float* G = ws + 2162688;          // 640*128*32 cplx

  rfft2_fused_kernel<<<256, 512, 0, stream>>>(f, kern, Fv, Kv);
  conv_mul_kernel<<<2112, 256, 0, stream>>>(Fv, Kv, CVv);
  irfft_stepA_kernel<<<640, 256, 0, stream>>>(CVv, Fv, G);
  irfft_stepB_kernel<<<640, 256, 0, stream>>>(G, out);
  cross_kernel<<<1024, 256, 0, stream>>>(out);
}

// Round 4
// 232.332 us; speedup vs baseline: 1.6675x; 1.1267x over previous
//
#include <hip/hip_runtime.h>

// EquivariantLayer on MI355X (gfx950).
// f[16][8][64][64], kernel[1][8][16][64][64] -> out[16][128][128][128]
//
// Pipeline (scratch in d_ws: F 4.3MB, K 4.3MB, G 21MB):
//   1. rfft2_fused     : 256 blocks -> Fv[128][2112] cplx, Kv[128][2112] cplx
//   2. irfft_stepA_fused: 640 blocks. uv imgs (<512): on-the-fly conv
//        CV[b,j] = sum_i F[b,i] K[i,j], * TO_U/TO_V, x-inverse -> G
//        fr imgs (>=512): from F directly. Residue-class trick:
//        G[x0+32m] = sum_r i^{rm} S_r, S_r = sum_{ks mod4==r} C[ks] W^{kk x0}
//   3. stepB_fr        : 128 blocks, y-inverse -> out channels 0..7
//   4. uvcross         : 512 blocks = (b, x-strip of 4). Stage 32 uv-channel
//        G rows in LDS, finish y-inverse per (x,y0)/(x,y0+64) in registers,
//        write all 120 cross products u_i v_j - u_j v_i -> channels 8..127.
//
// DFT conventions: scale=(ky==0?2:4)/16384; ks<=32 -> kk=ks, ks>=33 -> kk=ks+64;
// nyquist row ks==32 / col ky==32 zeroed at staging (so ks=32 twiddle is moot).

#define PI_D 3.14159265358979323846

// ---------------- 1. forward rfft2 of 64x64 images (f + symmetrized kernel) --
__global__ __launch_bounds__(512) void rfft2_fused_kernel(
    const float* __restrict__ f, const float* __restrict__ kern,
    float* __restrict__ Fv, float* __restrict__ Kv) {
  __shared__ float s_raw[64][65];                 // padded: transposed reads conflict-free
  __shared__ float s_fe[64][32];
  __shared__ float s_fo[64][32];
  __shared__ __align__(16) float2 s_f[64][33];
  __shared__ float2 s_tw[64];

  const int bid = blockIdx.x;
  const int tid = threadIdx.x;
  const int sym = (bid >= 128);
  const float* img = sym ? (kern + (size_t)(bid - 128) * 4096)
                         : (f + (size_t)bid * 4096);
  float* dst = sym ? (Kv + (size_t)(bid - 128) * 4224)
                   : (Fv + (size_t)bid * 4224);

  if (tid < 64) {
    double a = -2.0 * PI_D * (double)tid / 64.0;  // forward sign
    s_tw[tid] = make_float2((float)cos(a), (float)sin(a));
  }
  for (int idx = tid; idx < 4096; idx += 512) {
    s_raw[idx >> 6][idx & 63] = img[idx];
  }
  __syncthreads();
  // symmetrize (kernel imgs) + parity fold along y
  for (int o = tid; o < 2048; o += 512) {
    int x = o >> 5, y = o & 31;
    float a0, a1;
    if (sym) {
      int i = x;
#pragma unroll
      for (int h = 0; h < 2; ++h) {
        int j = y + 32 * h;
        int ni = (64 - i) & 63, nj = (64 - j) & 63;
        float v = (s_raw[i][j] + s_raw[nj][i] + s_raw[ni][nj] + s_raw[j][ni] +
                   s_raw[j][i] + s_raw[i][nj] + s_raw[nj][ni] + s_raw[ni][j]) *
                  0.125f;
        if (h == 0) a0 = v; else a1 = v;
      }
    } else {
      a0 = s_raw[x][y];
      a1 = s_raw[x][y + 32];
    }
    s_fe[x][y] = a0 + a1;
    s_fo[x][y] = a0 - a1;
  }
  __syncthreads();
  // pass 1: rows along y (real -> 33 cplx), recurrence twiddles
  for (int o = tid; o < 2112; o += 512) {
    int x = o / 33, ky = o - x * 33;
    const float* row = (ky & 1) ? s_fo[x] : s_fe[x];
    float2 w1 = s_tw[ky];
    float wr = 1.f, wi = 0.f, re = 0.f, im = 0.f;
#pragma unroll 8
    for (int y = 0; y < 32; ++y) {
      float a = row[y];
      re += a * wr;
      im += a * wi;
      float nr = wr * w1.x - wi * w1.y;
      wi = wr * w1.y + wi * w1.x;
      wr = nr;
    }
    s_f[x][ky] = make_float2(re, im);
  }
  __syncthreads();
  // pass 2: cols along x, output pairs (kx0, kx0+32) via x-parity
  for (int o = tid; o < 1056; o += 512) {
    int kx0 = o / 33, ky = o - kx0 * 33;
    float2 w1 = s_tw[kx0];
    float wr = 1.f, wi = 0.f;
    float er = 0.f, ei = 0.f, orr = 0.f, oi = 0.f;
#pragma unroll 8
    for (int x = 0; x < 64; ++x) {
      float2 cv = s_f[x][ky];
      float pr = cv.x * wr - cv.y * wi;
      float pi = cv.x * wi + cv.y * wr;
      if (x & 1) { orr += pr; oi += pi; } else { er += pr; ei += pi; }
      float nr = wr * w1.x - wi * w1.y;
      wi = wr * w1.y + wi * w1.x;
      wr = nr;
    }
    float2* o2 = (float2*)dst;
    o2[kx0 * 33 + ky] = make_float2(er + orr, ei + oi);
    o2[(kx0 + 32) * 33 + ky] = make_float2(er - orr, ei - oi);
  }
}

// ---------------- 2. step A: on-the-fly conv + x-inverse, residue-class -------
__global__ __launch_bounds__(256) void irfft_stepA_fused_kernel(
    const float* __restrict__ Fv, const float* __restrict__ Kv,
    float* __restrict__ G) {
  __shared__ __align__(16) float2 s_c[64][34];
  __shared__ float2 s_tw[128];
  const int img = blockIdx.x;
  const int tid = threadIdx.x;
  const int is_uv = (img < 512);

  if (tid < 128) {
    double a = 2.0 * PI_D * (double)tid / 128.0;  // inverse sign
    s_tw[tid] = make_float2((float)cos(a), (float)sin(a));
  }

  const float2* F2 = (const float2*)Fv;
  const float2* K2 = (const float2*)Kv;
  if (is_uv) {
    const int b = img >> 5, r = img & 31, j = r >> 1, ph = r & 1;
    for (int o = tid; o < 2112; o += 256) {
      int ks = o / 33, ky = o - ks * 33;
      // conv on the fly: CV = sum_i F[b,i] * K[i,j]
      float re = 0.f, im = 0.f;
#pragma unroll
      for (int i = 0; i < 8; ++i) {
        float2 fv = F2[(size_t)(b * 8 + i) * 2112 + o];
        float2 kv = K2[(size_t)(i * 16 + j) * 2112 + o];
        re += fv.x * kv.x - fv.y * kv.y;
        im += fv.x * kv.y + fv.y * kv.x;
      }
      float scale = ((ky == 0) ? 2.0f : 4.0f) * (1.0f / 16384.0f);
      if (ks == 32 || ky == 32) scale = 0.0f;
      int kx = (ks <= 32) ? ks : ks - 64;
      float fac = 0.0f;
      if ((kx | ky) != 0) {
        float invden = 1.0f / (float)(kx * kx + ky * ky);
        fac = (ph == 0) ? ((float)ky * invden) : (-(float)kx * invden);
      }
      fac *= scale;
      s_c[ks][ky] = make_float2(-im * fac, re * fac);  // (re,im)*(i*fac)
    }
  } else {
    const float2* src = F2 + (size_t)(img - 512) * 2112;
    for (int o = tid; o < 2112; o += 256) {
      int ks = o / 33, ky = o - ks * 33;
      float2 cv = src[o];
      float scale = ((ky == 0) ? 2.0f : 4.0f) * (1.0f / 16384.0f);
      if (ks == 32 || ky == 32) scale = 0.0f;
      s_c[ks][ky] = make_float2(cv.x * scale, cv.y * scale);
    }
  }
  __syncthreads();

  const int x0 = tid & 31;
  const int ky0 = (tid >> 5) * 4;

  float Sr[4][4], Si[4][4];  // [residue r][ky u]
#pragma unroll
  for (int r = 0; r < 4; ++r)
#pragma unroll
    for (int u = 0; u < 4; ++u) { Sr[r][u] = 0.f; Si[r][u] = 0.f; }

  const float2 w1 = s_tw[x0];
  float wr = 1.f, wi = 0.f;  // W^{kk*x0}
  // L1: ks = 0..31 (kk = ks)
  for (int kb = 0; kb < 32; kb += 4) {
#pragma unroll
    for (int r = 0; r < 4; ++r) {
      int ks = kb + r;
      float4 c01 = *(const float4*)(&s_c[ks][ky0]);
      float4 c23 = *(const float4*)(&s_c[ks][ky0 + 2]);
      Sr[r][0] += c01.x * wr - c01.y * wi;  Si[r][0] += c01.x * wi + c01.y * wr;
      Sr[r][1] += c01.z * wr - c01.w * wi;  Si[r][1] += c01.z * wi + c01.w * wr;
      Sr[r][2] += c23.x * wr - c23.y * wi;  Si[r][2] += c23.x * wi + c23.y * wr;
      Sr[r][3] += c23.z * wr - c23.w * wi;  Si[r][3] += c23.z * wi + c23.w * wr;
      float nr = wr * w1.x - wi * w1.y;
      wi = wr * w1.y + wi * w1.x;
      wr = nr;
    }
  }
  // L2: ks = 32..63 (kk = ks+64; ks==32 term is zero so its twiddle is moot)
  {
    float2 w0 = s_tw[(96 * x0) & 127];
    wr = w0.x; wi = w0.y;
  }
  for (int kb = 32; kb < 64; kb += 4) {
#pragma unroll
    for (int r = 0; r < 4; ++r) {
      int ks = kb + r;
      float4 c01 = *(const float4*)(&s_c[ks][ky0]);
      float4 c23 = *(const float4*)(&s_c[ks][ky0 + 2]);
      Sr[r][0] += c01.x * wr - c01.y * wi;  Si[r][0] += c01.x * wi + c01.y * wr;
      Sr[r][1] += c01.z * wr - c01.w * wi;  Si[r][1] += c01.z * wi + c01.w * wr;
      Sr[r][2] += c23.x * wr - c23.y * wi;  Si[r][2] += c23.x * wi + c23.y * wr;
      Sr[r][3] += c23.z * wr - c23.w * wi;  Si[r][3] += c23.z * wi + c23.w * wr;
      float nr = wr * w1.x - wi * w1.y;
      wi = wr * w1.y + wi * w1.x;
      wr = nr;
    }
  }

  // combine: G[x0+32m] = sum_r i^{r*m} S_r
  float2* Gp = (float2*)G + (size_t)img * 128 * 32;
#pragma unroll
  for (int u = 0; u < 4; ++u) {
    int ky = ky0 + u;
    float ar = Sr[0][u] + Sr[2][u], ai = Si[0][u] + Si[2][u];
    float br = Sr[0][u] - Sr[2][u], bi = Si[0][u] - Si[2][u];
    float cr = Sr[1][u] + Sr[3][u], ci = Si[1][u] + Si[3][u];
    float dr = Sr[1][u] - Sr[3][u], di = Si[1][u] - Si[3][u];
    Gp[x0 * 32 + ky]        = make_float2(ar + cr, ai + ci);
    Gp[(x0 + 32) * 32 + ky] = make_float2(br - di, bi + dr);
    Gp[(x0 + 64) * 32 + ky] = make_float2(ar - cr, ai - ci);
    Gp[(x0 + 96) * 32 + ky] = make_float2(br + di, bi - dr);
  }
}

// ---------------- 3. step B for fr: y-inverse -> out channels 0..7 ----------
__global__ __launch_bounds__(256) void irfft_stepB_fr_kernel(
    const float* __restrict__ G, float* __restrict__ out) {
  __shared__ float2 s_tw[128];
  const int idx = blockIdx.x;          // 0..127 = b*8 + c
  const int img = 512 + idx;
  const int tid = threadIdx.x;
  if (tid < 128) {
    double a = 2.0 * PI_D * (double)tid / 128.0;
    s_tw[tid] = make_float2((float)cos(a), (float)sin(a));
  }
  __syncthreads();

  const int y0 = tid & 63, xg = tid >> 6;
  float* dst = out + ((size_t)(idx >> 3) * 128 + (idx & 7)) * 16384;

  float twr[32], twi[32];
  float2 w1 = s_tw[y0];
  twr[0] = 1.f; twi[0] = 0.f;
#pragma unroll
  for (int k = 1; k < 32; ++k) {
    twr[k] = twr[k - 1] * w1.x - twi[k - 1] * w1.y;
    twi[k] = twr[k - 1] * w1.y + twi[k - 1] * w1.x;
  }

  for (int xx = 0; xx < 32; ++xx) {
    int x = xg * 32 + xx;
    const float4* g4 = (const float4*)(G + ((size_t)img * 128 + x) * 64);
    float se = 0.f, so = 0.f;
#pragma unroll
    for (int m = 0; m < 16; ++m) {
      float4 g = g4[m];
      se += g.x * twr[2 * m] - g.y * twi[2 * m];
      so += g.z * twr[2 * m + 1] - g.w * twi[2 * m + 1];
    }
    dst[x * 128 + y0] = se + so;
    dst[x * 128 + y0 + 64] = se - so;
  }
}

// ---------------- 4. uv y-inverse + cross products fused --------------------
// block = (b, x-strip of 4). Thread = (xi = tid>>6, y0 = tid&63); computes all
// 32 uv channels at (x, y0) and (x, y0+64), then 120 crosses at both points.
__global__ __launch_bounds__(256) void uvcross_kernel(
    const float* __restrict__ G, float* __restrict__ out) {
  __shared__ __align__(16) float2 s_g[32][4][32];  // [ch][xi][ky]
  __shared__ float2 s_tw[128];
  const int b = blockIdx.x >> 5;
  const int x0s = (blockIdx.x & 31) * 4;
  const int tid = threadIdx.x;
  if (tid < 128) {
    double a = 2.0 * PI_D * (double)tid / 128.0;
    s_tw[tid] = make_float2((float)cos(a), (float)sin(a));
  }
  // stage 32 channel-rows (b's uv imgs are G imgs b*32 + c)
  const float4* gsrc = (const float4*)G;
  float4* s4 = (float4*)s_g;
  for (int u = tid; u < 2048; u += 256) {
    int q = u & 15, xi = (u >> 4) & 3, ch = u >> 6;
    s4[u] = gsrc[(((size_t)(b * 32 + ch) * 128 + x0s + xi) << 4) + q];
  }
  __syncthreads();

  const int y0 = tid & 63, xi = tid >> 6;
  float twr[32], twi[32];
  float2 w1 = s_tw[y0];
  twr[0] = 1.f; twi[0] = 0.f;
#pragma unroll
  for (int k = 1; k < 32; ++k) {
    twr[k] = twr[k - 1] * w1.x - twi[k - 1] * w1.y;
    twi[k] = twr[k - 1] * w1.y + twi[k - 1] * w1.x;
  }

  float a0[32], a1[32];  // channel values at (x,y0) and (x,y0+64)
#pragma unroll
  for (int c = 0; c < 32; ++c) {
    const float4* gg = (const float4*)&s_g[c][xi][0];
    float se = 0.f, so = 0.f;
#pragma unroll
    for (int m = 0; m < 16; ++m) {
      float4 g = gg[m];
      se += g.x * twr[2 * m] - g.y * twi[2 * m];
      so += g.z * twr[2 * m + 1] - g.w * twi[2 * m + 1];
    }
    a0[c] = se + so;
    a1[c] = se - so;
  }

  // crosses: u_i = ch 2i, v_j = ch 2j+1
  float* dst = out + ((size_t)b * 128 + 8) * 16384 + (size_t)(x0s + xi) * 128 + y0;
  int pp = 0;
#pragma unroll
  for (int i = 0; i < 15; ++i) {
#pragma unroll
    for (int j = i + 1; j < 16; ++j) {
      dst[(size_t)pp * 16384] = a0[2 * i] * a0[2 * j + 1] - a0[2 * j] * a0[2 * i + 1];
      dst[(size_t)pp * 16384 + 64] = a1[2 * i] * a1[2 * j + 1] - a1[2 * j] * a1[2 * i + 1];
      ++pp;
    }
  }
}

extern "C" void kernel_launch(void* const* d_in, const int* in_sizes, int n_in,
                              void* d_out, int out_size, void* d_ws, size_t ws_size,
                              hipStream_t stream) {
  const float* f = (const float*)d_in[0];     // [16][8][64][64]
  const float* kern = (const float*)d_in[1];  // [1][8][16][64][64]
  float* out = (float*)d_out;                 // [16][128][128][128]
  float* ws = (float*)d_ws;

  float* Fv = ws;                   // 128 imgs * 2112 cplx = 540672 floats
  float* Kv = ws + 540672;          // 540672 floats
  float* G = ws + 1081344;          // 640*128*32 cplx = 5242880 floats

  rfft2_fused_kernel<<<256, 512, 0, stream>>>(f, kern, Fv, Kv);
  irfft_stepA_fused_kernel<<<640, 256, 0, stream>>>(Fv, Kv, G);
  irfft_stepB_fr_kernel<<<128, 256, 0, stream>>>(G, out);
  uvcross_kernel<<<512, 256, 0, stream>>>(G, out);
}

// Round 5
// 207.245 us; speedup vs baseline: 1.8694x; 1.1210x over previous
//
#include <hip/hip_runtime.h>

// EquivariantLayer on MI355X (gfx950).
// f[16][8][64][64], kernel[1][8][16][64][64] -> out[16][128][128][128]
//
// Pipeline (scratch in d_ws: F 4.3MB, K 4.3MB, G 21MB):
//   1. rfft2_fused : 256 blocks -> Fv[128][2112] cplx, Kv[128][2112] cplx
//   2. irfft_stepA_fused : 640 blocks. uv imgs (<512): on-the-fly conv
//        CV[b,j] = sum_i F[b,i] K[i,j], * TO_U/TO_V, x-inverse -> G[img][x][ky]
//        fr imgs (>=512): from F directly. Residue-class trick:
//        G[x0+32m] = sum_r i^{rm} S_r, S_r = sum_{ks mod4==r} C[ks] W^{kk x0}
//        Thread map (x0=tid>>3, ky0=(tid&7)*4) -> wave stores are contiguous 2KB.
//   3. finishB : 512 blocks = (b, x-strip of 4). Stage 40 G rows (32 uv + 8 fr)
//        in LDS, finish y-inverse per (x,y0)/(x,y0+64) in registers; write fr
//        channels 0..7 and all 120 crosses u_i v_j - u_j v_i -> channels 8..127.
//
// DFT conventions: scale=(ky==0?2:4)/16384; ks<=32 -> kk=ks, ks>=33 -> kk=ks+64;
// nyquist row ks==32 / col ky==32 zeroed at staging (so ks=32 twiddle is moot).

#define PI_D 3.14159265358979323846

// ---------------- 1. forward rfft2 of 64x64 images (f + symmetrized kernel) --
__global__ __launch_bounds__(512) void rfft2_fused_kernel(
    const float* __restrict__ f, const float* __restrict__ kern,
    float* __restrict__ Fv, float* __restrict__ Kv) {
  __shared__ float s_raw[64][65];                  // padded: transposed reads conflict-free
  __shared__ __align__(16) float s_fe[64][36];     // stride 36: float4-aligned, distinct banks
  __shared__ __align__(16) float s_fo[64][36];
  __shared__ __align__(16) float2 s_f[64][33];
  __shared__ float2 s_tw[64];

  const int bid = blockIdx.x;
  const int tid = threadIdx.x;
  const int sym = (bid >= 128);
  const float* img = sym ? (kern + (size_t)(bid - 128) * 4096)
                         : (f + (size_t)bid * 4096);
  float* dst = sym ? (Kv + (size_t)(bid - 128) * 4224)
                   : (Fv + (size_t)bid * 4224);

  if (tid < 64) {
    double a = -2.0 * PI_D * (double)tid / 64.0;  // forward sign
    s_tw[tid] = make_float2((float)cos(a), (float)sin(a));
  }
  for (int idx = tid; idx < 4096; idx += 512) {
    s_raw[idx >> 6][idx & 63] = img[idx];
  }
  __syncthreads();
  // symmetrize (kernel imgs) + parity fold along y
  for (int o = tid; o < 2048; o += 512) {
    int x = o >> 5, y = o & 31;
    float a0, a1;
    if (sym) {
      int i = x;
#pragma unroll
      for (int h = 0; h < 2; ++h) {
        int j = y + 32 * h;
        int ni = (64 - i) & 63, nj = (64 - j) & 63;
        float v = (s_raw[i][j] + s_raw[nj][i] + s_raw[ni][nj] + s_raw[j][ni] +
                   s_raw[j][i] + s_raw[i][nj] + s_raw[nj][ni] + s_raw[ni][j]) *
                  0.125f;
        if (h == 0) a0 = v; else a1 = v;
      }
    } else {
      a0 = s_raw[x][y];
      a1 = s_raw[x][y + 32];
    }
    s_fe[x][y] = a0 + a1;
    s_fo[x][y] = a0 - a1;
  }
  __syncthreads();
  // pass 1: rows along y (real -> 33 cplx), float4 reads + recurrence twiddles
  for (int o = tid; o < 2112; o += 512) {
    int x = o / 33, ky = o - x * 33;
    const float4* row4 = (const float4*)((ky & 1) ? s_fo[x] : s_fe[x]);
    float2 w1 = s_tw[ky];
    float wr = 1.f, wi = 0.f, re = 0.f, im = 0.f;
#pragma unroll
    for (int y4 = 0; y4 < 8; ++y4) {
      float4 a4 = row4[y4];
      float nr;
      re += a4.x * wr; im += a4.x * wi;
      nr = wr * w1.x - wi * w1.y; wi = wr * w1.y + wi * w1.x; wr = nr;
      re += a4.y * wr; im += a4.y * wi;
      nr = wr * w1.x - wi * w1.y; wi = wr * w1.y + wi * w1.x; wr = nr;
      re += a4.z * wr; im += a4.z * wi;
      nr = wr * w1.x - wi * w1.y; wi = wr * w1.y + wi * w1.x; wr = nr;
      re += a4.w * wr; im += a4.w * wi;
      nr = wr * w1.x - wi * w1.y; wi = wr * w1.y + wi * w1.x; wr = nr;
    }
    s_f[x][ky] = make_float2(re, im);
  }
  __syncthreads();
  // pass 2: cols along x, output pairs (kx0, kx0+32) via x-parity
  for (int o = tid; o < 1056; o += 512) {
    int kx0 = o / 33, ky = o - kx0 * 33;
    float2 w1 = s_tw[kx0];
    float wr = 1.f, wi = 0.f;
    float er = 0.f, ei = 0.f, orr = 0.f, oi = 0.f;
#pragma unroll 8
    for (int x = 0; x < 64; ++x) {
      float2 cv = s_f[x][ky];
      float pr = cv.x * wr - cv.y * wi;
      float pi = cv.x * wi + cv.y * wr;
      if (x & 1) { orr += pr; oi += pi; } else { er += pr; ei += pi; }
      float nr = wr * w1.x - wi * w1.y;
      wi = wr * w1.y + wi * w1.x;
      wr = nr;
    }
    float2* o2 = (float2*)dst;
    o2[kx0 * 33 + ky] = make_float2(er + orr, ei + oi);
    o2[(kx0 + 32) * 33 + ky] = make_float2(er - orr, ei - oi);
  }
}

// ---------------- 2. step A: on-the-fly conv + x-inverse, residue-class -------
// thread: x0 = tid>>3 (covers x0,+32,+64,+96), ky0 = (tid&7)*4
__global__ __launch_bounds__(256) void irfft_stepA_fused_kernel(
    const float* __restrict__ Fv, const float* __restrict__ Kv,
    float* __restrict__ G) {
  __shared__ __align__(16) float2 s_c[64][34];
  __shared__ float2 s_tw[128];
  const int img = blockIdx.x;
  const int tid = threadIdx.x;
  const int is_uv = (img < 512);

  if (tid < 128) {
    double a = 2.0 * PI_D * (double)tid / 128.0;  // inverse sign
    s_tw[tid] = make_float2((float)cos(a), (float)sin(a));
  }

  const float2* F2 = (const float2*)Fv;
  const float2* K2 = (const float2*)Kv;
  if (is_uv) {
    const int b = img >> 5, r = img & 31, j = r >> 1, ph = r & 1;
    for (int o = tid; o < 2112; o += 256) {
      int ks = o / 33, ky = o - ks * 33;
      float re = 0.f, im = 0.f;
#pragma unroll
      for (int i = 0; i < 8; ++i) {
        float2 fv = F2[(size_t)(b * 8 + i) * 2112 + o];
        float2 kv = K2[(size_t)(i * 16 + j) * 2112 + o];
        re += fv.x * kv.x - fv.y * kv.y;
        im += fv.x * kv.y + fv.y * kv.x;
      }
      float scale = ((ky == 0) ? 2.0f : 4.0f) * (1.0f / 16384.0f);
      if (ks == 32 || ky == 32) scale = 0.0f;
      int kx = (ks <= 32) ? ks : ks - 64;
      float fac = 0.0f;
      if ((kx | ky) != 0) {
        float invden = 1.0f / (float)(kx * kx + ky * ky);
        fac = (ph == 0) ? ((float)ky * invden) : (-(float)kx * invden);
      }
      fac *= scale;
      s_c[ks][ky] = make_float2(-im * fac, re * fac);  // (re,im)*(i*fac)
    }
  } else {
    const float2* src = F2 + (size_t)(img - 512) * 2112;
    for (int o = tid; o < 2112; o += 256) {
      int ks = o / 33, ky = o - ks * 33;
      float2 cv = src[o];
      float scale = ((ky == 0) ? 2.0f : 4.0f) * (1.0f / 16384.0f);
      if (ks == 32 || ky == 32) scale = 0.0f;
      s_c[ks][ky] = make_float2(cv.x * scale, cv.y * scale);
    }
  }
  __syncthreads();

  const int x0 = tid >> 3;
  const int ky0 = (tid & 7) * 4;

  float Sr[4][4], Si[4][4];  // [residue r][ky u]
#pragma unroll
  for (int r = 0; r < 4; ++r)
#pragma unroll
    for (int u = 0; u < 4; ++u) { Sr[r][u] = 0.f; Si[r][u] = 0.f; }

  const float2 w1 = s_tw[x0];
  float wr = 1.f, wi = 0.f;  // W^{kk*x0}
  // L1: ks = 0..31 (kk = ks)
  for (int kb = 0; kb < 32; kb += 4) {
#pragma unroll
    for (int r = 0; r < 4; ++r) {
      int ks = kb + r;
      float4 c01 = *(const float4*)(&s_c[ks][ky0]);
      float4 c23 = *(const float4*)(&s_c[ks][ky0 + 2]);
      Sr[r][0] += c01.x * wr - c01.y * wi;  Si[r][0] += c01.x * wi + c01.y * wr;
      Sr[r][1] += c01.z * wr - c01.w * wi;  Si[r][1] += c01.z * wi + c01.w * wr;
      Sr[r][2] += c23.x * wr - c23.y * wi;  Si[r][2] += c23.x * wi + c23.y * wr;
      Sr[r][3] += c23.z * wr - c23.w * wi;  Si[r][3] += c23.z * wi + c23.w * wr;
      float nr = wr * w1.x - wi * w1.y;
      wi = wr * w1.y + wi * w1.x;
      wr = nr;
    }
  }
  // L2: ks = 32..63 (kk = ks+64; ks==32 term is zero so its twiddle is moot)
  {
    float2 w0 = s_tw[(96 * x0) & 127];
    wr = w0.x; wi = w0.y;
  }
  for (int kb = 32; kb < 64; kb += 4) {
#pragma unroll
    for (int r = 0; r < 4; ++r) {
      int ks = kb + r;
      float4 c01 = *(const float4*)(&s_c[ks][ky0]);
      float4 c23 = *(const float4*)(&s_c[ks][ky0 + 2]);
      Sr[r][0] += c01.x * wr - c01.y * wi;  Si[r][0] += c01.x * wi + c01.y * wr;
      Sr[r][1] += c01.z * wr - c01.w * wi;  Si[r][1] += c01.z * wi + c01.w * wr;
      Sr[r][2] += c23.x * wr - c23.y * wi;  Si[r][2] += c23.x * wi + c23.y * wr;
      Sr[r][3] += c23.z * wr - c23.w * wi;  Si[r][3] += c23.z * wi + c23.w * wr;
      float nr = wr * w1.x - wi * w1.y;
      wi = wr * w1.y + wi * w1.x;
      wr = nr;
    }
  }

  // combine: G[x0+32m] = sum_r i^{r*m} S_r ; coalesced float4 stores
  float2 vals[4][4];  // [m][u]
#pragma unroll
  for (int u = 0; u < 4; ++u) {
    float ar = Sr[0][u] + Sr[2][u], ai = Si[0][u] + Si[2][u];
    float br = Sr[0][u] - Sr[2][u], bi = Si[0][u] - Si[2][u];
    float cr = Sr[1][u] + Sr[3][u], ci = Si[1][u] + Si[3][u];
    float dr = Sr[1][u] - Sr[3][u], di = Si[1][u] - Si[3][u];
    vals[0][u] = make_float2(ar + cr, ai + ci);
    vals[1][u] = make_float2(br - di, bi + dr);
    vals[2][u] = make_float2(ar - cr, ai - ci);
    vals[3][u] = make_float2(br + di, bi - dr);
  }
  float2* Gp = (float2*)G + (size_t)img * 4096;
#pragma unroll
  for (int m = 0; m < 4; ++m) {
    int x = x0 + 32 * m;
    float4* q = (float4*)(Gp + (size_t)x * 32 + ky0);
    q[0] = make_float4(vals[m][0].x, vals[m][0].y, vals[m][1].x, vals[m][1].y);
    q[1] = make_float4(vals[m][2].x, vals[m][2].y, vals[m][3].x, vals[m][3].y);
  }
}

// ---------------- 3. finishB: y-inverse for 40 channels + cross products -----
// block = (b, x-strip of 4). Thread = (xi = tid>>6, y0 = tid&63).
// ch 0..31 = uv (G img b*32+ch), ch 32..39 = fr (G img 512+b*8+(ch-32)).
__global__ __launch_bounds__(256) void finishB_kernel(
    const float* __restrict__ G, float* __restrict__ out) {
  __shared__ __align__(16) float2 s_g[40][4][32];  // [ch][xi][ky]
  __shared__ float2 s_tw[128];
  const int b = blockIdx.x >> 5;
  const int x0s = (blockIdx.x & 31) * 4;
  const int tid = threadIdx.x;
  if (tid < 128) {
    double a = 2.0 * PI_D * (double)tid / 128.0;
    s_tw[tid] = make_float2((float)cos(a), (float)sin(a));
  }
  const float4* gsrc = (const float4*)G;
  float4* s4 = (float4*)s_g;
  for (int u = tid; u < 2560; u += 256) {
    int q = u & 15, xi = (u >> 4) & 3, ch = u >> 6;
    int gim = (ch < 32) ? (b * 32 + ch) : (512 + b * 8 + (ch - 32));
    s4[u] = gsrc[(((size_t)gim * 128 + x0s + xi) << 4) + q];
  }
  __syncthreads();

  const int y0 = tid & 63, xi = tid >> 6;
  const int x = x0s + xi;
  float twr[32], twi[32];
  float2 w1 = s_tw[y0];
  twr[0] = 1.f; twi[0] = 0.f;
#pragma unroll
  for (int k = 1; k < 32; ++k) {
    twr[k] = twr[k - 1] * w1.x - twi[k - 1] * w1.y;
    twi[k] = twr[k - 1] * w1.y + twi[k - 1] * w1.x;
  }

  // fr channels first (registers released immediately)
#pragma unroll
  for (int c = 0; c < 8; ++c) {
    const float4* gg = (const float4*)&s_g[32 + c][xi][0];
    float se = 0.f, so = 0.f;
#pragma unroll
    for (int m = 0; m < 16; ++m) {
      float4 g = gg[m];
      se += g.x * twr[2 * m] - g.y * twi[2 * m];
      so += g.z * twr[2 * m + 1] - g.w * twi[2 * m + 1];
    }
    float* dstf = out + ((size_t)b * 128 + c) * 16384 + (size_t)x * 128 + y0;
    dstf[0] = se + so;
    dstf[64] = se - so;
  }

  // uv channels, kept live for the crosses
  float a0[32], a1[32];
#pragma unroll
  for (int c = 0; c < 32; ++c) {
    const float4* gg = (const float4*)&s_g[c][xi][0];
    float se = 0.f, so = 0.f;
#pragma unroll
    for (int m = 0; m < 16; ++m) {
      float4 g = gg[m];
      se += g.x * twr[2 * m] - g.y * twi[2 * m];
      so += g.z * twr[2 * m + 1] - g.w * twi[2 * m + 1];
    }
    a0[c] = se + so;
    a1[c] = se - so;
  }

  // crosses: u_i = ch 2i, v_j = ch 2j+1
  float* dst = out + ((size_t)b * 128 + 8) * 16384 + (size_t)x * 128 + y0;
  int pp = 0;
#pragma unroll
  for (int i = 0; i < 15; ++i) {
#pragma unroll
    for (int j = i + 1; j < 16; ++j) {
      dst[(size_t)pp * 16384] = a0[2 * i] * a0[2 * j + 1] - a0[2 * j] * a0[2 * i + 1];
      dst[(size_t)pp * 16384 + 64] = a1[2 * i] * a1[2 * j + 1] - a1[2 * j] * a1[2 * i + 1];
      ++pp;
    }
  }
}

extern "C" void kernel_launch(void* const* d_in, const int* in_sizes, int n_in,
                              void* d_out, int out_size, void* d_ws, size_t ws_size,
                              hipStream_t stream) {
  const float* f = (const float*)d_in[0];     // [16][8][64][64]
  const float* kern = (const float*)d_in[1];  // [1][8][16][64][64]
  float* out = (float*)d_out;                 // [16][128][128][128]
  float* ws = (float*)d_ws;

  float* Fv = ws;                   // 128 imgs * 2112 cplx = 540672 floats
  float* Kv = ws + 540672;          // 540672 floats
  float* G = ws + 1081344;          // 640*128*32 cplx = 5242880 floats

  rfft2_fused_kernel<<<256, 512, 0, stream>>>(f, kern, Fv, Kv);
  irfft_stepA_fused_kernel<<<640, 256, 0, stream>>>(Fv, Kv, G);
  finishB_kernel<<<512, 256, 0, stream>>>(G, out);
}